// Round 1
// baseline (623.217 us; speedup 1.0000x reference)
//
#include <hip/hip_runtime.h>
#include <stdint.h>

typedef __attribute__((ext_vector_type(8))) __bf16 bf16x8;
typedef __attribute__((ext_vector_type(4))) float  f32x4;

// ---------- helpers ----------
__device__ __forceinline__ uint16_t f2b(float f) {           // fp32 -> bf16 RNE
  uint32_t u = __float_as_uint(f);
  u += 0x7fffu + ((u >> 16) & 1u);
  return (uint16_t)(u >> 16);
}
__device__ __forceinline__ float b2f_lo(uint32_t p) { return __uint_as_float(p << 16); }
__device__ __forceinline__ float b2f_hi(uint32_t p) { return __uint_as_float(p & 0xffff0000u); }

// branch-free tanh: 1 - 2/(e^{2x}+1); saturates correctly at +-1
__device__ __forceinline__ float tanh_fast(float x) {
  float e = __expf(2.0f * x);
  return 1.0f - 2.0f / (e + 1.0f);
}

// raw barrier with compiler memory fence (no hardware waitcnt drain)
__device__ __forceinline__ void bar() { asm volatile("s_barrier" ::: "memory"); }
__device__ __forceinline__ void wait_vm0() { asm volatile("s_waitcnt vmcnt(0)" ::: "memory"); }

// async 16B global -> LDS (DMA, no VGPR round trip). LDS dest = wave-uniform
// base + lane*16 (linear); swizzle is applied on the GLOBAL source address.
__device__ __forceinline__ void gload16(const void* g, void* l) {
  __builtin_amdgcn_global_load_lds(
      (__attribute__((address_space(1))) uint32_t*)g,
      (__attribute__((address_space(3))) uint32_t*)l, 16, 0, 0);
}

// ---------- 1. encoder fp32 -> bf16 (8 elems/thread) ----------
__global__ __launch_bounds__(256) void convert_enc(const float4* __restrict__ in,
                                                   uint4* __restrict__ out) {
  int i = blockIdx.x * 256 + threadIdx.x;
  float4 a = in[2 * i], b = in[2 * i + 1];
  uint4 o;
  o.x = (uint32_t)f2b(a.x) | ((uint32_t)f2b(a.y) << 16);
  o.y = (uint32_t)f2b(a.z) | ((uint32_t)f2b(a.w) << 16);
  o.z = (uint32_t)f2b(b.x) | ((uint32_t)f2b(b.y) << 16);
  o.w = (uint32_t)f2b(b.z) | ((uint32_t)f2b(b.w) << 16);
  out[i] = o;
}

// ---------- 2. W_a (K x N) -> WT bf16 (N x K), LDS-tiled transpose ----------
__global__ __launch_bounds__(256) void convert_WT(const float* __restrict__ W,
                                                  uint16_t* __restrict__ WT) {
  __shared__ float tile[64][65];
  int k0 = (blockIdx.x & 15) * 64;
  int n0 = (blockIdx.x >> 4) * 64;
  #pragma unroll
  for (int it = 0; it < 16; ++it) {
    int idx = it * 256 + threadIdx.x;
    int kr = idx >> 6, nc = idx & 63;
    tile[kr][nc] = W[(size_t)(k0 + kr) * 1024 + n0 + nc];
  }
  __syncthreads();
  #pragma unroll
  for (int it = 0; it < 16; ++it) {
    int idx = it * 256 + threadIdx.x;
    int nr = idx >> 6, kc = idx & 63;
    WT[(size_t)(n0 + nr) * 1024 + k0 + kc] = f2b(tile[kc][nr]);
  }
}

// ---------- 3. u[b,f] += sum_{d in seg} dec_last[b,d] * U[d,f]  (fp32, atomic) ----
__global__ __launch_bounds__(256) void compute_u(const float* __restrict__ dec,
                                                 const float4* __restrict__ U4,
                                                 float* __restrict__ u) {
  int b = blockIdx.x >> 3, dseg = blockIdx.x & 7;
  __shared__ float sdec[128];
  if (threadIdx.x < 128)
    sdec[threadIdx.x] = dec[(size_t)b * 64 * 1024 + 63 * 1024 + dseg * 128 + threadIdx.x];
  __syncthreads();
  float4 a = {0.f, 0.f, 0.f, 0.f};
  const float4* Ub = U4 + (size_t)dseg * 128 * 256 + threadIdx.x;
  #pragma unroll 4
  for (int d = 0; d < 128; ++d) {
    float4 w = Ub[(size_t)d * 256];
    float s = sdec[d];
    a.x = fmaf(s, w.x, a.x);
    a.y = fmaf(s, w.y, a.y);
    a.z = fmaf(s, w.z, a.z);
    a.w = fmaf(s, w.w, a.w);
  }
  float* up = u + b * 1024 + threadIdx.x * 4;
  atomicAdd(up + 0, a.x);
  atomicAdd(up + 1, a.y);
  atomicAdd(up + 2, a.z);
  atomicAdd(up + 3, a.w);
}

// ---------- 4. fused GEMM: 256x256 tile, 8-wave, 4-phase/K-tile schedule ------
// spart[ntile][row] = sum_{f in ntile's 256 cols} v[f]*tanh((A@W)[row,f]+u[b,f])
//
// Structure (CDNA4 8-phase template): BM=BN=256, BK=64, 512 threads = 8 waves
// (2M x 4N), wave tile 128x64. LDS 128KiB: [dbuf][A0,A1,B0,B1][128x64 bf16].
// Staging: global_load_lds width-16, LINEAR LDS dest; XOR swizzle
// byte ^= ((row&7)<<4) applied on the pre-swizzled GLOBAL source and again on
// the ds_read address (involution) -> conflict-free ds_read_b128.
// Per K-tile: 4 phases {ds_read frags | stage next-tile halves (phases 0,1) |
// s_barrier | setprio(1) 16xMFMA setprio(0) | (phase3: vmcnt(0)) s_barrier}.
// Loads for kt+1 are issued at kt phases 0/1 and only drained at kt phase 3 —
// in flight across 2-3 phases of MFMA (counted-vmcnt discipline, never mid-loop
// full drains beyond the next tile's own loads).
__global__ __launch_bounds__(512, 2) void gemm_score(const uint16_t* __restrict__ A,
                                                     const uint16_t* __restrict__ BT,
                                                     const float* __restrict__ u,
                                                     const float* __restrict__ v,
                                                     float* __restrict__ spart) {
  __shared__ uint4 lds4[2][4][1024];  // [dbuf][A-half0,A-half1,B-half0,B-half1][16KB]
  __shared__ float sred[4][256];

  // XCD-bijective swizzle (nwg=1024, 1024%8==0): each XCD gets 128 consecutive
  // logical tiles = 32 mtiles x 4 ntiles -> A-panel reuse lands in one L2.
  const int bx = blockIdx.x;
  const int wg = (bx & 7) * 128 + (bx >> 3);
  const int mtile = wg >> 2;  // 0..255
  const int ntile = wg & 3;   // 0..3

  const int tid = threadIdx.x;
  const int lane = tid & 63;
  const int wid = tid >> 6;   // 0..7
  const int wr = wid >> 2;    // 0..1  : A half (row block of 128)
  const int wc = wid & 3;     // 0..3  : 64-col group
  const int nib = lane & 15;
  const int q4 = lane >> 4;

  const int rowA = mtile * 256;
  const char* baseA = (const char*)A + (size_t)rowA * 2048;
  const char* baseB = (const char*)BT + (size_t)ntile * 256 * 2048;
  // staging: chunk L = l*512 + tid; row = L>>3; 16B col-chunk c = L&7,
  // pre-swizzled source chunk = c ^ (row&7). rows for l=1 are +64 (same c swz).
  const size_t rowoff = (size_t)(tid >> 3) * 2048 +
                        (size_t)(((tid & 7) ^ ((tid >> 3) & 7)) << 4);

#define STAGE2(nbuf, h, srcbase)                                      \
  do {                                                                \
    const char* _s = (srcbase);                                       \
    gload16(_s + rowoff,             &lds4[nbuf][h][wid * 64]);       \
    gload16(_s + rowoff + 64 * 2048, &lds4[nbuf][h][512 + wid * 64]); \
  } while (0)

  f32x4 acc[8][4];
  #pragma unroll
  for (int i = 0; i < 8; ++i)
    #pragma unroll
    for (int j = 0; j < 4; ++j) acc[i][j] = (f32x4){0.f, 0.f, 0.f, 0.f};

  // prologue: stage K-tile 0 into buf 0
  STAGE2(0, 0, baseA);
  STAGE2(0, 1, baseA + 128 * 2048);
  STAGE2(0, 2, baseB);
  STAGE2(0, 3, baseB + 128 * 2048);
  wait_vm0();
  bar();

  bf16x8 bfr[4];
  const int bhalf = 2 + (wc >> 1);
  const int ncol0 = (wc & 1) * 64;

  #pragma unroll 2
  for (int kt = 0; kt < 16; ++kt) {
    const int cb = kt & 1, nb = cb ^ 1;
    const char* nA = baseA + (size_t)(kt + 1) * 128;
    const char* nB = baseB + (size_t)(kt + 1) * 128;
    #pragma unroll
    for (int q = 0; q < 4; ++q) {
      const int qi = q & 1, kk = q >> 1;            // phases: (0,0)(1,0)(0,1)(1,1)
      const int kx = (kk * 4 + q4) ^ (nib & 7);     // swizzled 16B k-chunk
      bf16x8 af[4];
      #pragma unroll
      for (int i = 0; i < 4; ++i)
        af[i] = *(const bf16x8*)&lds4[cb][wr][(qi * 64 + i * 16 + nib) * 8 + kx];
      if (qi == 0) {  // B frags persist across the two qi phases of this kk
        #pragma unroll
        for (int j = 0; j < 4; ++j)
          bfr[j] = *(const bf16x8*)&lds4[cb][bhalf][(ncol0 + j * 16 + nib) * 8 + kx];
      }
      if (kt < 15) {  // issue next-tile halves early: A at phase 0, B at phase 1
        if (q == 0) {
          STAGE2(nb, 0, nA);
          STAGE2(nb, 1, nA + 128 * 2048);
        } else if (q == 1) {
          STAGE2(nb, 2, nB);
          STAGE2(nb, 3, nB + 128 * 2048);
        }
      }
      bar();
      __builtin_amdgcn_s_setprio(1);
      #pragma unroll
      for (int i = 0; i < 4; ++i)
        #pragma unroll
        for (int j = 0; j < 4; ++j)
          acc[qi * 4 + i][j] = __builtin_amdgcn_mfma_f32_16x16x32_bf16(
              af[i], bfr[j], acc[qi * 4 + i][j], 0, 0, 0);
      __builtin_amdgcn_s_setprio(0);
      if (q == 3) wait_vm0();  // next tile's 8 loads landed (issued >=2 phases ago)
      bar();
    }
  }
#undef STAGE2

  // ---- epilogue: v-weighted tanh row reduction -> spart[ntile][row] ----
  const int b = mtile >> 3;  // 256-row block is batch-uniform (2048 % 256 == 0)
  float vv[4], uu[4];
  #pragma unroll
  for (int j = 0; j < 4; ++j) {
    int col = ntile * 256 + wc * 64 + j * 16 + nib;
    vv[j] = v[col];
    uu[j] = u[b * 1024 + col];
  }
  #pragma unroll
  for (int qi = 0; qi < 2; ++qi)
    #pragma unroll
    for (int i = 0; i < 4; ++i)
      #pragma unroll
      for (int reg = 0; reg < 4; ++reg) {
        float s = 0.f;
        #pragma unroll
        for (int j = 0; j < 4; ++j) s += vv[j] * tanh_fast(acc[qi * 4 + i][j][reg] + uu[j]);
        s += __shfl_xor(s, 1);
        s += __shfl_xor(s, 2);
        s += __shfl_xor(s, 4);
        s += __shfl_xor(s, 8);
        if (nib == 0) sred[wc][wr * 128 + qi * 64 + i * 16 + q4 * 4 + reg] = s;
      }
  __syncthreads();
  if (tid < 256) {
    float s = sred[0][tid] + sred[1][tid] + sred[2][tid] + sred[3][tid];
    spart[(size_t)ntile * 65536 + rowA + tid] = s;
  }
}

// ---------- 5. softmax over t (2048) per batch; sums the 4 ntile partials ------
__global__ __launch_bounds__(256) void softmax_k(const float* __restrict__ spart,
                                                 float* __restrict__ wout) {
  int b = blockIdx.x, tid = threadIdx.x;
  __shared__ float red[4];
  float sv[8];
  float mx = -1e30f;
  #pragma unroll
  for (int i = 0; i < 8; ++i) {
    int idx = b * 2048 + i * 256 + tid;
    float s = 0.f;
    #pragma unroll
    for (int j = 0; j < 4; ++j) s += spart[j * 65536 + idx];
    sv[i] = s;
    mx = fmaxf(mx, s);
  }
  #pragma unroll
  for (int off = 1; off < 64; off <<= 1) mx = fmaxf(mx, __shfl_xor(mx, off));
  if ((tid & 63) == 0) red[tid >> 6] = mx;
  __syncthreads();
  mx = fmaxf(fmaxf(red[0], red[1]), fmaxf(red[2], red[3]));
  __syncthreads();
  float sum = 0.f;
  #pragma unroll
  for (int i = 0; i < 8; ++i) {
    sv[i] = __expf(sv[i] - mx);
    sum += sv[i];
  }
  #pragma unroll
  for (int off = 1; off < 64; off <<= 1) sum += __shfl_xor(sum, off);
  if ((tid & 63) == 0) red[tid >> 6] = sum;
  __syncthreads();
  float inv = 1.0f / (red[0] + red[1] + red[2] + red[3]);
  #pragma unroll
  for (int i = 0; i < 8; ++i) wout[b * 2048 + i * 256 + tid] = sv[i] * inv;
}

// ---------- 6. context[b,e] = sum_t w[b,t] * enc[b,t,e]; 32 t-chunks of 64 ----
__global__ __launch_bounds__(256) void context_k(const uint16_t* __restrict__ encA,
                                                 const float* __restrict__ w,
                                                 float* __restrict__ ctx) {
  int b = blockIdx.x >> 5, ch = blockIdx.x & 31;
  int t0 = ch * 64;
  __shared__ float lw[64];
  if (threadIdx.x < 64) lw[threadIdx.x] = w[b * 2048 + t0 + threadIdx.x];
  __syncthreads();
  int e0 = threadIdx.x * 4;
  float a0 = 0.f, a1 = 0.f, a2 = 0.f, a3 = 0.f;
  const uint16_t* base = encA + (size_t)b * 2048 * 1024 + (size_t)t0 * 1024 + e0;
  #pragma unroll 4
  for (int t = 0; t < 64; ++t) {
    uint2 p = *(const uint2*)(base + (size_t)t * 1024);
    float wt = lw[t];
    a0 = fmaf(wt, b2f_lo(p.x), a0);
    a1 = fmaf(wt, b2f_hi(p.x), a1);
    a2 = fmaf(wt, b2f_lo(p.y), a2);
    a3 = fmaf(wt, b2f_hi(p.y), a3);
  }
  atomicAdd(&ctx[b * 1024 + e0 + 0], a0);
  atomicAdd(&ctx[b * 1024 + e0 + 1], a1);
  atomicAdd(&ctx[b * 1024 + e0 + 2], a2);
  atomicAdd(&ctx[b * 1024 + e0 + 3], a3);
}

extern "C" void kernel_launch(void* const* d_in, const int* in_sizes, int n_in,
                              void* d_out, int out_size, void* d_ws, size_t ws_size,
                              hipStream_t stream) {
  const float* enc = (const float*)d_in[0];  // (32, 2048, 1024)
  const float* dec = (const float*)d_in[1];  // (32, 64, 1024)
  const float* Wa  = (const float*)d_in[2];  // (1024, 1024)
  const float* Ua  = (const float*)d_in[3];  // (1024, 1024)
  const float* Va  = (const float*)d_in[4];  // (1024, 1)

  float* out = (float*)d_out;
  float* ctx = out;                 // 32*1024
  float* wts = out + 32 * 1024;     // 32*2048*1

  char* ws = (char*)d_ws;
  uint16_t* encA  = (uint16_t*)ws;                           // 128 MB bf16 encoder
  uint16_t* WT    = (uint16_t*)(ws + 134217728);             // 2 MB bf16 W^T
  float*    ub    = (float*)  (ws + 136314880);              // 128 KB u[b,f]
  float*    spart = (float*)  (ws + 136445952);              // 1 MB score partials [4][65536]

  hipMemsetAsync(ctx, 0, 32 * 1024 * sizeof(float), stream);
  hipMemsetAsync(ub, 0, 32 * 1024 * sizeof(float), stream);

  convert_enc<<<32768, 256, 0, stream>>>((const float4*)enc, (uint4*)encA);
  convert_WT<<<256, 256, 0, stream>>>(Wa, WT);
  compute_u<<<256, 256, 0, stream>>>(dec, (const float4*)Ua, ub);
  gemm_score<<<1024, 512, 0, stream>>>(encA, WT, ub, Va, spart);
  softmax_k<<<32, 256, 0, stream>>>(spart, wts);
  context_k<<<1024, 256, 0, stream>>>(encA, wts, ctx);
}